// Round 4
// baseline (363.943 us; speedup 1.0000x reference)
//
#include <hip/hip_runtime.h>
#include <math.h>

#define Bn 64
#define Sn 512
#define Hn 768
#define ATT_H 100
#define CLS_H 300
#define Mtok (Bn*Sn)          // 32768
#define NP 112                // padded ATT_H (7 x 16)
#define NT 7                  // col tiles of 16

#define W1T_N (NP*Hn)         // 86016
#define W3T_N (CLS_H*Hn)      // 230400
#define POOL_N (Bn*Hn)        // 49152

typedef __attribute__((ext_vector_type(8))) short short8;
typedef __attribute__((ext_vector_type(4))) float floatx4;   // native vec, ok for nontemporal builtins

__device__ inline float sigf(float x) { return 1.0f / (1.0f + expf(-x)); }

__device__ inline unsigned short f2bf(float x) {
    union { float f; unsigned int u; } v; v.f = x;
    unsigned int r = (v.u + 0x7FFFu + ((v.u >> 16) & 1u)) >> 16;
    return (unsigned short)r;
}

__device__ inline float wred_sum(float v) {
    #pragma unroll
    for (int d = 32; d; d >>= 1) v += __shfl_down(v, d, 64);
    return v;
}
__device__ inline float wred_max(float v) {
    #pragma unroll
    for (int d = 32; d; d >>= 1) v = fmaxf(v, __shfl_down(v, d, 64));
    return v;
}
__device__ inline float wred_min(float v) {
    #pragma unroll
    for (int d = 32; d; d >>= 1) v = fminf(v, __shfl_down(v, d, 64));
    return v;
}

// ---------------------------------------------------------------------------
// K0: prep. w1t[n][k] = bf16(W1[k][n]) zero-padded to 112 rows; w3t[j][k] =
// W3[k][j] (fp32); b1w2[n] = (b1[n], W2[n]) padded; zero pooled and zpart.
// ---------------------------------------------------------------------------
__global__ __launch_bounds__(256) void k0_prep(
    const float* __restrict__ W1, const float* __restrict__ b1,
    const float* __restrict__ W2, const float* __restrict__ W3,
    unsigned short* __restrict__ w1t, float* __restrict__ b1w2,
    float* __restrict__ w3t, float* __restrict__ pooled,
    float* __restrict__ zpart)
{
    int idx = blockIdx.x * 256 + threadIdx.x;
    if (idx < W1T_N) {
        int n = idx / Hn, k = idx - n * Hn;
        float v = (n < ATT_H) ? W1[(size_t)k * ATT_H + n] : 0.f;
        w1t[idx] = f2bf(v);
    } else if (idx < W1T_N + W3T_N) {
        int i = idx - W1T_N;
        int j = i / Hn, k = i - j * Hn;
        w3t[i] = W3[(size_t)k * CLS_H + j];
    } else if (idx < W1T_N + W3T_N + NP) {
        int j = idx - (W1T_N + W3T_N);
        b1w2[2 * j]     = (j < ATT_H) ? b1[j] : 0.f;
        b1w2[2 * j + 1] = (j < ATT_H) ? W2[j] : 0.f;
    } else if (idx < W1T_N + W3T_N + NP + POOL_N) {
        pooled[idx - (W1T_N + W3T_N + NP)] = 0.f;
    } else if (idx < W1T_N + W3T_N + NP + POOL_N + 5 * Bn) {
        zpart[idx - (W1T_N + W3T_N + NP + POOL_N)] = 0.f;
    }
}

// ---------------------------------------------------------------------------
// K1: token_att = sigmoid(tanh(h @ W1 + b1) @ W2 + b2) via bf16 MFMA, fused
// with the hidden_states passthrough copy (nontemporal stores keep h resident
// in L3 for K3). Barrier-free: each wave independently owns 16 tokens; A-frags
// loaded straight from global in fragment layout (lane(u,q): row u, floats
// q*8..q*8+8 of each 32-float k-tile), B-frags from L1/L2-resident w1t.
// 512 blocks x 4 waves = 8 waves/CU, no __syncthreads anywhere.
// ---------------------------------------------------------------------------
__global__ __launch_bounds__(256) void k1_att(
    const float* __restrict__ h, const unsigned short* __restrict__ w1t,
    const float* __restrict__ b1w2, const float* __restrict__ b2,
    float* __restrict__ out_hidden, float* __restrict__ att)
{
    const int tid = threadIdx.x;
    const int wave = tid >> 6, lane = tid & 63;
    const int u = lane & 15, q = lane >> 4;
    const int t0 = (blockIdx.x * 4 + wave) * 16;
    const size_t rb = (size_t)(t0 + u) * Hn + q * 8;
    const unsigned short* wp = w1t + (size_t)u * Hn + q * 8;

    floatx4 acc[NT];
    #pragma unroll
    for (int ct = 0; ct < NT; ct++) acc[ct] = (floatx4)0.f;

    #pragma unroll 4
    for (int kk = 0; kk < Hn / 32; kk++) {
        const floatx4* hp = (const floatx4*)(h + rb + kk * 32);
        floatx4 v0 = hp[0];
        floatx4 v1 = hp[1];
        floatx4* op = (floatx4*)(out_hidden + rb + kk * 32);
        __builtin_nontemporal_store(v0, op);
        __builtin_nontemporal_store(v1, op + 1);
        short8 a;
        a[0] = (short)f2bf(v0.x); a[1] = (short)f2bf(v0.y);
        a[2] = (short)f2bf(v0.z); a[3] = (short)f2bf(v0.w);
        a[4] = (short)f2bf(v1.x); a[5] = (short)f2bf(v1.y);
        a[6] = (short)f2bf(v1.z); a[7] = (short)f2bf(v1.w);
        #pragma unroll
        for (int ct = 0; ct < NT; ct++) {
            short8 bfr = *(const short8*)(wp + (size_t)ct * 16 * Hn + kk * 32);
            acc[ct] = __builtin_amdgcn_mfma_f32_16x16x32_bf16(a, bfr, acc[ct], 0, 0, 0);
        }
    }

    // epilogue: z[token] = sum_n tanh(D[token][n] + b1[n]) * W2[n]
    float z[4] = {0.f, 0.f, 0.f, 0.f};
    #pragma unroll
    for (int ct = 0; ct < NT; ct++) {
        float2 bw = *(const float2*)(b1w2 + (ct * 16 + u) * 2);
        #pragma unroll
        for (int r = 0; r < 4; r++)
            z[r] += tanhf(acc[ct][r] + bw.x) * bw.y;
    }
    #pragma unroll
    for (int mask = 1; mask < 16; mask <<= 1) {
        #pragma unroll
        for (int r = 0; r < 4; r++) z[r] += __shfl_xor(z[r], mask, 64);
    }
    if (u == 0) {
        float bb2 = b2[0];
        #pragma unroll
        for (int r = 0; r < 4; r++)
            att[t0 + q * 4 + r] = sigf(z[r] + bb2);
    }
}

// ---------------------------------------------------------------------------
// K2: per batch row — segmented max (reversed Hillis-Steele), masking,
// per-row reductions. One block per batch row. (verified in R1/R2)
// ---------------------------------------------------------------------------
__global__ __launch_bounds__(256) void k2_seg(
    const float* __restrict__ att, const int* __restrict__ offset,
    const float* __restrict__ labels, float* __restrict__ masked_out,
    float* __restrict__ sum_m, float* __restrict__ slab_o,
    float* __restrict__ tl_o, float* __restrict__ mino_o,
    float* __restrict__ maxm_o)
{
    const int b = blockIdx.x, tid = threadIdx.x;
    __shared__ float attl[Sn];
    __shared__ int   startl[Sn];
    __shared__ float v0[Sn], v1[Sn];
    __shared__ int   f0[Sn], f1[Sn];
    __shared__ float rsum[4], rtl[4], rsl[4], rmn[4], rmx[4];

    for (int s = tid; s < Sn; s += 256) {
        attl[s] = att[b * Sn + s];
        startl[s] = (offset[(size_t)(b * Sn + s) * 2] == 0) ? 1 : 0;
    }
    __syncthreads();
    for (int i = tid; i < Sn; i += 256) {
        int s = Sn - 1 - i;
        int endf = (s == Sn - 1) ? 1 : startl[s + 1];
        v0[i] = attl[s];
        f0[i] = endf;
    }
    __syncthreads();

    float* va = v0; float* vb = v1;
    int* fa = f0; int* fb = f1;
    for (int d = 1; d < Sn; d <<= 1) {
        for (int i = tid; i < Sn; i += 256) {
            float v = va[i]; int f = fa[i];
            float nv = v; int nf = f;
            if (i >= d) {
                if (!f) nv = fmaxf(v, va[i - d]);
                nf = f | fa[i - d];
            }
            vb[i] = nv; fb[i] = nf;
        }
        __syncthreads();
        float* tv = va; va = vb; vb = tv;
        int* tf = fa; fa = fb; fb = tf;
    }

    float lsum = 0.f, ltl = 0.f, lslab = -1e30f, lmin = 1e30f, lmax = -1e30f;
    for (int s = tid; s < Sn; s += 256) {
        float lab = labels[b * Sn + s];
        int st = startl[s];
        float segm = va[Sn - 1 - s];
        float m = (st && lab != -1.0f) ? segm : 0.f;
        masked_out[b * Sn + s] = m;
        lsum += m;
        float zl = (lab == 1.0f) ? 1.f : 0.f;
        ltl += (m - zl) * (m - zl);
        lslab = fmaxf(lslab, lab);
        float om = (m == 0.f) ? 1.f : m;
        lmin = fminf(lmin, om);
        lmax = fmaxf(lmax, m);
    }
    int wid = tid >> 6, lane = tid & 63;
    lsum = wred_sum(lsum); ltl = wred_sum(ltl);
    lslab = wred_max(lslab); lmin = wred_min(lmin); lmax = wred_max(lmax);
    if (lane == 0) { rsum[wid]=lsum; rtl[wid]=ltl; rsl[wid]=lslab; rmn[wid]=lmin; rmx[wid]=lmax; }
    __syncthreads();
    if (tid == 0) {
        sum_m[b]  = rsum[0]+rsum[1]+rsum[2]+rsum[3];
        tl_o[b]   = rtl[0]+rtl[1]+rtl[2]+rtl[3];
        slab_o[b] = fmaxf(fmaxf(rsl[0],rsl[1]), fmaxf(rsl[2],rsl[3]));
        mino_o[b] = fminf(fminf(rmn[0],rmn[1]), fminf(rmn[2],rmn[3]));
        maxm_o[b] = fmaxf(fmaxf(rmx[0],rmx[1]), fmaxf(rmx[2],rmx[3]));
    }
}

// ---------------------------------------------------------------------------
// K3: pooled[b,:] += sum_s h[b,s,:] * masked[b,s]/sum_m[b] over a 32-row
// s-chunk. grid (64 b, 16 sc) x 192 threads = 12 waves/CU, fully coalesced
// (192 threads x float4 = one 3KB row per pass). fp32 atomicAdd partials.
// ---------------------------------------------------------------------------
__global__ __launch_bounds__(192) void k3_pool(
    const float* __restrict__ h, const float* __restrict__ masked,
    const float* __restrict__ sum_m, float* __restrict__ pooled)
{
    const int b = blockIdx.x, sc = blockIdx.y;
    const int tid = threadIdx.x;
    __shared__ float nrm[32];
    if (tid < 32)
        nrm[tid] = masked[b * Sn + sc * 32 + tid] * (1.0f / sum_m[b]);
    __syncthreads();
    const floatx4* hp = (const floatx4*)(h + ((size_t)b * Sn + sc * 32) * Hn) + tid;
    float ax = 0.f, ay = 0.f, az = 0.f, aw = 0.f;
    #pragma unroll 8
    for (int s = 0; s < 32; s++) {
        floatx4 v = hp[(size_t)s * (Hn / 4)];
        float w = nrm[s];
        ax += v.x * w; ay += v.y * w; az += v.z * w; aw += v.w * w;
    }
    float* pp = pooled + (size_t)b * Hn + tid * 4;
    atomicAdd(pp + 0, ax); atomicAdd(pp + 1, ay);
    atomicAdd(pp + 2, az); atomicAdd(pp + 3, aw);
}

// ---------------------------------------------------------------------------
// K4: zpart[jc,b] = sum_{j in chunk} tanh(pooled[b]·W3T[j] + b3[j]) * W4[j].
// grid (64 b, 5 jc) x 256 threads; 4 threads per j, float4 dot over k.
// ---------------------------------------------------------------------------
__global__ __launch_bounds__(256) void k4_sent(
    const float* __restrict__ pooled, const float* __restrict__ w3t,
    const float* __restrict__ b3, const float* __restrict__ W4,
    float* __restrict__ zpart)
{
    const int b = blockIdx.x, jc = blockIdx.y;
    const int tid = threadIdx.x;
    __shared__ __align__(16) float pl[Hn];
    __shared__ float yred[64];
    for (int k = tid; k < Hn; k += 256) pl[k] = pooled[(size_t)b * Hn + k];
    if (tid < 64) yred[tid] = 0.f;
    __syncthreads();
    int jj = tid >> 2, ks = tid & 3;
    float a = 0.f;
    if (jj < 60) {
        int j = jc * 60 + jj;
        const floatx4* wr = (const floatx4*)(w3t + (size_t)j * Hn) + ks * 48;
        const floatx4* pr = (const floatx4*)pl + ks * 48;
        #pragma unroll 8
        for (int i = 0; i < 48; i++) {
            floatx4 wv = wr[i]; floatx4 pv = pr[i];
            a += wv.x * pv.x + wv.y * pv.y + wv.z * pv.z + wv.w * pv.w;
        }
    }
    a += __shfl_xor(a, 1, 64);
    a += __shfl_xor(a, 2, 64);
    if (jj < 60 && ks == 0) {
        int j = jc * 60 + jj;
        yred[jj] = tanhf(a + b3[j]) * W4[j];
    }
    __syncthreads();
    if (tid < 64) {
        float y = yred[tid];
        y = wred_sum(y);
        if (tid == 0) zpart[jc * Bn + b] = y;
    }
}

// ---------------------------------------------------------------------------
// K5: sent + final scalars. One wave; b = lane.
// ---------------------------------------------------------------------------
__global__ __launch_bounds__(64) void k5_loss(
    const float* __restrict__ zpart, const float* __restrict__ b4,
    const float* __restrict__ slab, const float* __restrict__ tl,
    const float* __restrict__ mino, const float* __restrict__ maxm,
    float* __restrict__ out, float* __restrict__ out_sent)
{
    int t = threadIdx.x;
    float z = b4[0];
    #pragma unroll
    for (int jc = 0; jc < 5; jc++) z += zpart[jc * Bn + t];
    float sent = sigf(z);
    out_sent[t] = sent;
    float sl = slab[t];
    float e1 = (sent - sl) * (sent - sl);
    float e2 = tl[t];
    float e3 = mino[t] * mino[t];
    float mm = maxm[t] - sl;
    float e4 = mm * mm;
    e1 = wred_sum(e1); e2 = wred_sum(e2); e3 = wred_sum(e3); e4 = wred_sum(e4);
    if (t == 0) {
        out[1] = e1;
        out[2] = e2;
        out[3] = e3;
        out[4] = e4;
        out[0] = e1 + e2 + 0.01f * (e3 + e4);
    }
}

extern "C" void kernel_launch(void* const* d_in, const int* in_sizes, int n_in,
                              void* d_out, int out_size, void* d_ws, size_t ws_size,
                              hipStream_t stream) {
    (void)in_sizes; (void)n_in; (void)out_size; (void)ws_size;
    const float* h      = (const float*)d_in[0];
    const int*   offset = (const int*)d_in[1];
    const float* labels = (const float*)d_in[2];
    const float* W1     = (const float*)d_in[3];
    const float* b1     = (const float*)d_in[4];
    const float* W2     = (const float*)d_in[5];
    const float* b2     = (const float*)d_in[6];
    const float* W3     = (const float*)d_in[7];
    const float* b3     = (const float*)d_in[8];
    const float* W4     = (const float*)d_in[9];
    const float* b4     = (const float*)d_in[10];

    float* out        = (float*)d_out;
    float* out_hidden = out + 5;
    float* out_masked = out_hidden + (size_t)Bn * Sn * Hn;   // 25,165,824
    float* out_sent   = out_masked + (size_t)Bn * Sn;        // 32,768

    float* ws      = (float*)d_ws;
    float* att     = ws;                        // 32768
    float* sum_m   = att + Mtok;                // 64
    float* slab    = sum_m + Bn;
    float* tlb     = slab + Bn;
    float* mino    = tlb + Bn;
    float* maxm    = mino + Bn;
    float* pooled  = maxm + Bn;                 // 49152
    float* zpart   = pooled + POOL_N;           // 320
    float* b1w2    = zpart + 5 * Bn;            // 224
    float* w3t     = b1w2 + 2 * NP;             // 230400
    unsigned short* w1t = (unsigned short*)(w3t + W3T_N);  // 86016 bf16

    int k0_total = W1T_N + W3T_N + NP + POOL_N + 5 * Bn;
    k0_prep<<<(k0_total + 255) / 256, 256, 0, stream>>>(W1, b1, W2, W3,
                                                        w1t, b1w2, w3t, pooled, zpart);
    k1_att<<<Mtok / 64, 256, 0, stream>>>(h, w1t, b1w2, b2, out_hidden, att);
    k2_seg<<<Bn, 256, 0, stream>>>(att, offset, labels, out_masked,
                                   sum_m, slab, tlb, mino, maxm);
    k3_pool<<<dim3(Bn, 16), 192, 0, stream>>>(h, out_masked, sum_m, pooled);
    k4_sent<<<dim3(Bn, 5), 256, 0, stream>>>(pooled, w3t, b3, W4, zpart);
    k5_loss<<<1, 64, 0, stream>>>(zpart, b4, slab, tlb, mino, maxm, out, out_sent);
}

// Round 5
// 302.592 us; speedup vs baseline: 1.2028x; 1.2028x over previous
//
#include <hip/hip_runtime.h>
#include <math.h>

#define Bn 64
#define Sn 512
#define Hn 768
#define ATT_H 100
#define CLS_H 300
#define Mtok (Bn*Sn)          // 32768
#define NP 112                // padded ATT_H (7 x 16)
#define NT 7                  // col tiles of 16

#define W1T_N (NP*Hn)         // 86016
#define W3T_N (CLS_H*Hn)      // 230400
#define POOL_N (Bn*Hn)        // 49152

#define KCH 256               // k-chunk staged per iteration
#define LDA2 264              // bf16 elems per LDS row (256 + 8 pad, 16B-aligned)

typedef __attribute__((ext_vector_type(8))) short short8;
typedef __attribute__((ext_vector_type(4))) float floatx4;

__device__ inline float sigf(float x) { return 1.0f / (1.0f + expf(-x)); }

__device__ inline unsigned short f2bf(float x) {
    union { float f; unsigned int u; } v; v.f = x;
    unsigned int r = (v.u + 0x7FFFu + ((v.u >> 16) & 1u)) >> 16;
    return (unsigned short)r;
}

__device__ inline float wred_sum(float v) {
    #pragma unroll
    for (int d = 32; d; d >>= 1) v += __shfl_down(v, d, 64);
    return v;
}
__device__ inline float wred_max(float v) {
    #pragma unroll
    for (int d = 32; d; d >>= 1) v = fmaxf(v, __shfl_down(v, d, 64));
    return v;
}
__device__ inline float wred_min(float v) {
    #pragma unroll
    for (int d = 32; d; d >>= 1) v = fminf(v, __shfl_down(v, d, 64));
    return v;
}

// ---------------------------------------------------------------------------
// K0: prep. w1t[n][k] = bf16(W1[k][n]) zero-padded to 112 rows; w3t[j][k] =
// W3[k][j] (fp32); b1w2[n] = (b1[n], W2[n]) padded; zero pooled and zpart.
// ---------------------------------------------------------------------------
__global__ __launch_bounds__(256) void k0_prep(
    const float* __restrict__ W1, const float* __restrict__ b1,
    const float* __restrict__ W2, const float* __restrict__ W3,
    unsigned short* __restrict__ w1t, float* __restrict__ b1w2,
    float* __restrict__ w3t, float* __restrict__ pooled,
    float* __restrict__ zpart)
{
    int idx = blockIdx.x * 256 + threadIdx.x;
    if (idx < W1T_N) {
        int n = idx / Hn, k = idx - n * Hn;
        float v = (n < ATT_H) ? W1[(size_t)k * ATT_H + n] : 0.f;
        w1t[idx] = f2bf(v);
    } else if (idx < W1T_N + W3T_N) {
        int i = idx - W1T_N;
        int j = i / Hn, k = i - j * Hn;
        w3t[i] = W3[(size_t)k * CLS_H + j];
    } else if (idx < W1T_N + W3T_N + NP) {
        int j = idx - (W1T_N + W3T_N);
        b1w2[2 * j]     = (j < ATT_H) ? b1[j] : 0.f;
        b1w2[2 * j + 1] = (j < ATT_H) ? W2[j] : 0.f;
    } else if (idx < W1T_N + W3T_N + NP + POOL_N) {
        pooled[idx - (W1T_N + W3T_N + NP)] = 0.f;
    } else if (idx < W1T_N + W3T_N + NP + POOL_N + 5 * Bn) {
        zpart[idx - (W1T_N + W3T_N + NP + POOL_N)] = 0.f;
    }
}

// ---------------------------------------------------------------------------
// K1: token_att = sigmoid(tanh(h @ W1 + b1) @ W2 + b2) via bf16 MFMA, fused
// with the hidden_states passthrough copy (regular stores -> L2 write-back
// coalescing; nt stores caused 1.7x write amplification in R4).
// K-split x2 for occupancy: 512 threads (8 waves)/block, 64 tokens/block.
// Wave w: tile tl=w&3 (tokens tl*16..+16), k-group g=w>>2 (half of each
// 256-k chunk). Staging is block-wide coalesced float4; A enters MFMA from
// LDS; B (w1t) streams from L1/L2. acc pairs combined via LDS at the end.
// 512 blocks x 8 waves = 4096 waves = 16 waves/CU.
// ---------------------------------------------------------------------------
__global__ __launch_bounds__(512, 4) void k1_att(
    const float* __restrict__ h, const unsigned short* __restrict__ w1t,
    const float* __restrict__ b1w2, const float* __restrict__ b2,
    float* __restrict__ out_hidden, float* __restrict__ att)
{
    __shared__ unsigned short As[64 * LDA2];   // 33792 B (reused for acc combine)

    const int tid = threadIdx.x;
    const int wave = tid >> 6, lane = tid & 63;
    const int u = lane & 15, q = lane >> 4;
    const int tl = wave & 3, g = wave >> 2;
    const int t0 = blockIdx.x * 64;
    const int srow = tid >> 6, sc4 = tid & 63;   // staging coords

    floatx4 acc[NT];
    #pragma unroll
    for (int ct = 0; ct < NT; ct++) acc[ct] = (floatx4)0.f;

    for (int it = 0; it < 3; it++) {
        __syncthreads();   // protect As from previous iteration's consumers
        #pragma unroll
        for (int j = 0; j < 8; j++) {
            int row = srow + j * 8;
            size_t gidx = (size_t)(t0 + row) * Hn + it * KCH + sc4 * 4;
            floatx4 v = *(const floatx4*)(h + gidx);
            *(floatx4*)(out_hidden + gidx) = v;
            ushort4 bv;
            bv.x = f2bf(v.x); bv.y = f2bf(v.y);
            bv.z = f2bf(v.z); bv.w = f2bf(v.w);
            *(ushort4*)(&As[row * LDA2 + sc4 * 4]) = bv;
        }
        __syncthreads();
        #pragma unroll
        for (int kk = 0; kk < 4; kk++) {
            short8 a = *(const short8*)(&As[(tl * 16 + u) * LDA2 + g * 128 + kk * 32 + q * 8]);
            #pragma unroll
            for (int ct = 0; ct < NT; ct++) {
                const short8* bp = (const short8*)(w1t + (size_t)(ct * 16 + u) * Hn
                                                   + it * KCH + g * 128 + kk * 32 + q * 8);
                acc[ct] = __builtin_amdgcn_mfma_f32_16x16x32_bf16(a, *bp, acc[ct], 0, 0, 0);
            }
        }
    }

    // combine the two k-halves: waves g==1 dump accs to LDS, g==0 add.
    __syncthreads();
    float* cb = (float*)As;     // 4*64*28 = 7168 floats = 28 KB
    if (g == 1) {
        #pragma unroll
        for (int ct = 0; ct < NT; ct++)
            *(floatx4*)(&cb[(tl * 64 + lane) * 28 + ct * 4]) = acc[ct];
    }
    __syncthreads();
    if (g == 0) {
        #pragma unroll
        for (int ct = 0; ct < NT; ct++) {
            floatx4 o = *(const floatx4*)(&cb[(tl * 64 + lane) * 28 + ct * 4]);
            acc[ct] += o;
        }
        // epilogue: z[token] = sum_n tanh(D[token][n] + b1[n]) * W2[n]
        float z[4] = {0.f, 0.f, 0.f, 0.f};
        #pragma unroll
        for (int ct = 0; ct < NT; ct++) {
            float2 bw = *(const float2*)(b1w2 + (ct * 16 + u) * 2);
            #pragma unroll
            for (int r = 0; r < 4; r++)
                z[r] += tanhf(acc[ct][r] + bw.x) * bw.y;
        }
        #pragma unroll
        for (int mask = 1; mask < 16; mask <<= 1) {
            #pragma unroll
            for (int r = 0; r < 4; r++) z[r] += __shfl_xor(z[r], mask, 64);
        }
        if (u == 0) {
            float bb2 = b2[0];
            #pragma unroll
            for (int r = 0; r < 4; r++)
                att[t0 + tl * 16 + q * 4 + r] = sigf(z[r] + bb2);
        }
    }
}

// ---------------------------------------------------------------------------
// K2: per batch row — segmented max (reversed Hillis-Steele), masking,
// per-row reductions. One block per batch row. (verified R1-R4)
// ---------------------------------------------------------------------------
__global__ __launch_bounds__(256) void k2_seg(
    const float* __restrict__ att, const int* __restrict__ offset,
    const float* __restrict__ labels, float* __restrict__ masked_out,
    float* __restrict__ sum_m, float* __restrict__ slab_o,
    float* __restrict__ tl_o, float* __restrict__ mino_o,
    float* __restrict__ maxm_o)
{
    const int b = blockIdx.x, tid = threadIdx.x;
    __shared__ float attl[Sn];
    __shared__ int   startl[Sn];
    __shared__ float v0[Sn], v1[Sn];
    __shared__ int   f0[Sn], f1[Sn];
    __shared__ float rsum[4], rtl[4], rsl[4], rmn[4], rmx[4];

    for (int s = tid; s < Sn; s += 256) {
        attl[s] = att[b * Sn + s];
        startl[s] = (offset[(size_t)(b * Sn + s) * 2] == 0) ? 1 : 0;
    }
    __syncthreads();
    for (int i = tid; i < Sn; i += 256) {
        int s = Sn - 1 - i;
        int endf = (s == Sn - 1) ? 1 : startl[s + 1];
        v0[i] = attl[s];
        f0[i] = endf;
    }
    __syncthreads();

    float* va = v0; float* vb = v1;
    int* fa = f0; int* fb = f1;
    for (int d = 1; d < Sn; d <<= 1) {
        for (int i = tid; i < Sn; i += 256) {
            float v = va[i]; int f = fa[i];
            float nv = v; int nf = f;
            if (i >= d) {
                if (!f) nv = fmaxf(v, va[i - d]);
                nf = f | fa[i - d];
            }
            vb[i] = nv; fb[i] = nf;
        }
        __syncthreads();
        float* tv = va; va = vb; vb = tv;
        int* tf = fa; fa = fb; fb = tf;
    }

    float lsum = 0.f, ltl = 0.f, lslab = -1e30f, lmin = 1e30f, lmax = -1e30f;
    for (int s = tid; s < Sn; s += 256) {
        float lab = labels[b * Sn + s];
        int st = startl[s];
        float segm = va[Sn - 1 - s];
        float m = (st && lab != -1.0f) ? segm : 0.f;
        masked_out[b * Sn + s] = m;
        lsum += m;
        float zl = (lab == 1.0f) ? 1.f : 0.f;
        ltl += (m - zl) * (m - zl);
        lslab = fmaxf(lslab, lab);
        float om = (m == 0.f) ? 1.f : m;
        lmin = fminf(lmin, om);
        lmax = fmaxf(lmax, m);
    }
    int wid = tid >> 6, lane = tid & 63;
    lsum = wred_sum(lsum); ltl = wred_sum(ltl);
    lslab = wred_max(lslab); lmin = wred_min(lmin); lmax = wred_max(lmax);
    if (lane == 0) { rsum[wid]=lsum; rtl[wid]=ltl; rsl[wid]=lslab; rmn[wid]=lmin; rmx[wid]=lmax; }
    __syncthreads();
    if (tid == 0) {
        sum_m[b]  = rsum[0]+rsum[1]+rsum[2]+rsum[3];
        tl_o[b]   = rtl[0]+rtl[1]+rtl[2]+rtl[3];
        slab_o[b] = fmaxf(fmaxf(rsl[0],rsl[1]), fmaxf(rsl[2],rsl[3]));
        mino_o[b] = fminf(fminf(rmn[0],rmn[1]), fminf(rmn[2],rmn[3]));
        maxm_o[b] = fmaxf(fmaxf(rmx[0],rmx[1]), fmaxf(rmx[2],rmx[3]));
    }
}

// ---------------------------------------------------------------------------
// K3: pooled[b,:] += sum_s h[b,s,:] * masked[b,s]/sum_m[b] over a 16-row
// s-chunk. grid (64 b, 32 sc) x 192 threads = 24 waves/CU, fully coalesced.
// fp32 atomicAdd partials (32-way per address, pipelined through L2).
// ---------------------------------------------------------------------------
__global__ __launch_bounds__(192) void k3_pool(
    const float* __restrict__ h, const float* __restrict__ masked,
    const float* __restrict__ sum_m, float* __restrict__ pooled)
{
    const int b = blockIdx.x, sc = blockIdx.y;
    const int tid = threadIdx.x;
    __shared__ float nrm[16];
    if (tid < 16)
        nrm[tid] = masked[b * Sn + sc * 16 + tid] * (1.0f / sum_m[b]);
    __syncthreads();
    const floatx4* hp = (const floatx4*)(h + ((size_t)b * Sn + sc * 16) * Hn) + tid;
    float ax = 0.f, ay = 0.f, az = 0.f, aw = 0.f;
    #pragma unroll 8
    for (int s = 0; s < 16; s++) {
        floatx4 v = hp[(size_t)s * (Hn / 4)];
        float w = nrm[s];
        ax += v.x * w; ay += v.y * w; az += v.z * w; aw += v.w * w;
    }
    float* pp = pooled + (size_t)b * Hn + tid * 4;
    atomicAdd(pp + 0, ax); atomicAdd(pp + 1, ay);
    atomicAdd(pp + 2, az); atomicAdd(pp + 3, aw);
}

// ---------------------------------------------------------------------------
// K4: zpart[jc,b] = sum_{j in chunk} tanh(pooled[b]·W3T[j] + b3[j]) * W4[j].
// grid (64 b, 5 jc) x 256 threads; 4 threads per j, float4 dot over k.
// ---------------------------------------------------------------------------
__global__ __launch_bounds__(256) void k4_sent(
    const float* __restrict__ pooled, const float* __restrict__ w3t,
    const float* __restrict__ b3, const float* __restrict__ W4,
    float* __restrict__ zpart)
{
    const int b = blockIdx.x, jc = blockIdx.y;
    const int tid = threadIdx.x;
    __shared__ __align__(16) float pl[Hn];
    __shared__ float yred[64];
    for (int k = tid; k < Hn; k += 256) pl[k] = pooled[(size_t)b * Hn + k];
    if (tid < 64) yred[tid] = 0.f;
    __syncthreads();
    int jj = tid >> 2, ks = tid & 3;
    float a = 0.f;
    if (jj < 60) {
        int j = jc * 60 + jj;
        const floatx4* wr = (const floatx4*)(w3t + (size_t)j * Hn) + ks * 48;
        const floatx4* pr = (const floatx4*)pl + ks * 48;
        #pragma unroll 8
        for (int i = 0; i < 48; i++) {
            floatx4 wv = wr[i]; floatx4 pv = pr[i];
            a += wv.x * pv.x + wv.y * pv.y + wv.z * pv.z + wv.w * pv.w;
        }
    }
    a += __shfl_xor(a, 1, 64);
    a += __shfl_xor(a, 2, 64);
    if (jj < 60 && ks == 0) {
        int j = jc * 60 + jj;
        yred[jj] = tanhf(a + b3[j]) * W4[j];
    }
    __syncthreads();
    if (tid < 64) {
        float y = yred[tid];
        y = wred_sum(y);
        if (tid == 0) zpart[jc * Bn + b] = y;
    }
}

// ---------------------------------------------------------------------------
// K5: sent + final scalars. One wave; b = lane.
// ---------------------------------------------------------------------------
__global__ __launch_bounds__(64) void k5_loss(
    const float* __restrict__ zpart, const float* __restrict__ b4,
    const float* __restrict__ slab, const float* __restrict__ tl,
    const float* __restrict__ mino, const float* __restrict__ maxm,
    float* __restrict__ out, float* __restrict__ out_sent)
{
    int t = threadIdx.x;
    float z = b4[0];
    #pragma unroll
    for (int jc = 0; jc < 5; jc++) z += zpart[jc * Bn + t];
    float sent = sigf(z);
    out_sent[t] = sent;
    float sl = slab[t];
    float e1 = (sent - sl) * (sent - sl);
    float e2 = tl[t];
    float e3 = mino[t] * mino[t];
    float mm = maxm[t] - sl;
    float e4 = mm * mm;
    e1 = wred_sum(e1); e2 = wred_sum(e2); e3 = wred_sum(e3); e4 = wred_sum(e4);
    if (t == 0) {
        out[1] = e1;
        out[2] = e2;
        out[3] = e3;
        out[4] = e4;
        out[0] = e1 + e2 + 0.01f * (e3 + e4);
    }
}

extern "C" void kernel_launch(void* const* d_in, const int* in_sizes, int n_in,
                              void* d_out, int out_size, void* d_ws, size_t ws_size,
                              hipStream_t stream) {
    (void)in_sizes; (void)n_in; (void)out_size; (void)ws_size;
    const float* h      = (const float*)d_in[0];
    const int*   offset = (const int*)d_in[1];
    const float* labels = (const float*)d_in[2];
    const float* W1     = (const float*)d_in[3];
    const float* b1     = (const float*)d_in[4];
    const float* W2     = (const float*)d_in[5];
    const float* b2     = (const float*)d_in[6];
    const float* W3     = (const float*)d_in[7];
    const float* b3     = (const float*)d_in[8];
    const float* W4     = (const float*)d_in[9];
    const float* b4     = (const float*)d_in[10];

    float* out        = (float*)d_out;
    float* out_hidden = out + 5;
    float* out_masked = out_hidden + (size_t)Bn * Sn * Hn;   // 25,165,824
    float* out_sent   = out_masked + (size_t)Bn * Sn;        // 32,768

    float* ws      = (float*)d_ws;
    float* att     = ws;                        // 32768
    float* sum_m   = att + Mtok;                // 64
    float* slab    = sum_m + Bn;
    float* tlb     = slab + Bn;
    float* mino    = tlb + Bn;
    float* maxm    = mino + Bn;
    float* pooled  = maxm + Bn;                 // 49152
    float* zpart   = pooled + POOL_N;           // 320
    float* b1w2    = zpart + 5 * Bn;            // 224
    float* w3t     = b1w2 + 2 * NP;             // 230400
    unsigned short* w1t = (unsigned short*)(w3t + W3T_N);  // 86016 bf16

    int k0_total = W1T_N + W3T_N + NP + POOL_N + 5 * Bn;
    k0_prep<<<(k0_total + 255) / 256, 256, 0, stream>>>(W1, b1, W2, W3,
                                                        w1t, b1w2, w3t, pooled, zpart);
    k1_att<<<Mtok / 64, 512, 0, stream>>>(h, w1t, b1w2, b2, out_hidden, att);
    k2_seg<<<Bn, 256, 0, stream>>>(att, offset, labels, out_masked,
                                   sum_m, slab, tlb, mino, maxm);
    k3_pool<<<dim3(Bn, 32), 192, 0, stream>>>(h, out_masked, sum_m, pooled);
    k4_sent<<<dim3(Bn, 5), 256, 0, stream>>>(pooled, w3t, b3, W4, zpart);
    k5_loss<<<1, 64, 0, stream>>>(zpart, b4, slab, tlb, mino, maxm, out, out_sent);
}